// Round 1
// baseline (1729.274 us; speedup 1.0000x reference)
//
#include <hip/hip_runtime.h>
#include <hip/hip_bf16.h>

// DyGPrompt pretrain: 2-layer temporal graph attention.
// Decomposition:
//   t   = cos(ts*tw+tb)                                   (B,E)
//   TQ  = t@q_w.T + bq ; TK = t@k_wE.T + bk ; TV = t@v_wE.T + bv
//   NodeK/V = node_features @ {k,v}_wE.T                  (bf16 tables, layer-1 base)
//   EfK/V   = edge_features[edge_idx] @ {k,v}_wDE.T       (bf16, layer-invariant)
//   layer1: q = nf[nodes]@q_w.T + TQ ; k[b,kk] = NodeK[nb]+TK[b]+EfK[b,kk] ...
//   scatter: winner[node] = max sample idx (numpy last-write-wins)
//   layer2: base rows come from H1K/H1V (=h1@W) when winner[nb]>=0 else NodeK/V.
// ~46 GFLOP total vs 116 naive.

#define NSMP   12000
#define KNB    20
#define EDIM   172
#define HDIM   86
#define NNODES 100000

static __device__ __forceinline__ float bf2f(__hip_bfloat16 x) { return __bfloat162float(x); }

// ---------------- time encoding ----------------
__global__ __launch_bounds__(256) void time_enc_kernel(
    const float* __restrict__ ts, const float* __restrict__ tw,
    const float* __restrict__ tb, float* __restrict__ t)
{
    int i = blockIdx.x * 256 + threadIdx.x;
    if (i < NSMP * EDIM) {
        int b = i / EDIM, e = i - b * EDIM;
        t[i] = cosf(ts[b] * tw[e] + tb[e]);
    }
}

// ---------------- winner scatter (last write wins) ----------------
__global__ __launch_bounds__(256) void winner_init_kernel(int* __restrict__ w)
{
    int i = blockIdx.x * 256 + threadIdx.x;
    if (i < NNODES) w[i] = -1;
}
__global__ __launch_bounds__(256) void winner_scatter_kernel(
    const int* __restrict__ nodes, int* __restrict__ w)
{
    int i = blockIdx.x * 256 + threadIdx.x;
    if (i < NSMP) atomicMax(&w[nodes[i]], i);
}

// ---------------- generic GEMM: C = gather(A) @ B^T (+bias) ----------------
// Optional dual B/C sharing the A staging; f32 or bf16 C per output.
// 64x64 tile, 256 threads, 4x4 microtile, K-tile 16.
__global__ __launch_bounds__(256) void gemm_nt_kernel(
    const float* __restrict__ A, const int* __restrict__ Aidx, int lda, int M,
    const float* __restrict__ B1, const float* __restrict__ B2, int ldb,
    const float* __restrict__ bias1, const float* __restrict__ bias2,
    float* __restrict__ C1f, __hip_bfloat16* __restrict__ C1h,
    float* __restrict__ C2f, __hip_bfloat16* __restrict__ C2h,
    int N, int Kd)
{
    __shared__ __align__(16) float As[16][68];
    __shared__ __align__(16) float Bs1[16][68];
    __shared__ __align__(16) float Bs2[16][68];

    const int t  = threadIdx.x;
    const int tx = t & 15;
    const int ty = t >> 4;
    const int m0 = blockIdx.y * 64;
    const int n0 = blockIdx.x * 64;

    const int lr = t >> 2;          // 0..63 tile row
    const int lk = (t & 3) << 2;    // 0,4,8,12 k offset

    long arow = -1;
    {
        int am = m0 + lr;
        if (am < M) arow = Aidx ? (long)Aidx[am] : (long)am;
    }
    const int  bn   = n0 + lr;
    const bool bok  = bn < N;
    const bool dual = (B2 != nullptr);

    float acc1[4][4] = {};
    float acc2[4][4] = {};

    for (int k0 = 0; k0 < Kd; k0 += 16) {
        const int kb = k0 + lk;
        float4 av  = make_float4(0.f, 0.f, 0.f, 0.f);
        float4 bv1 = av, bv2 = av;
        if (arow >= 0) {
            if (kb + 3 < Kd) av = *(const float4*)(A + arow * (long)lda + kb);
            else {
                float* p = (float*)&av;
                for (int i = 0; i < 4; i++) if (kb + i < Kd) p[i] = A[arow * (long)lda + kb + i];
            }
        }
        if (bok) {
            const float* b1p = B1 + (long)bn * ldb;
            if (kb + 3 < Kd) {
                bv1 = *(const float4*)(b1p + kb);
                if (dual) bv2 = *(const float4*)(B2 + (long)bn * ldb + kb);
            } else {
                float* p1 = (float*)&bv1; float* p2 = (float*)&bv2;
                for (int i = 0; i < 4; i++) if (kb + i < Kd) {
                    p1[i] = b1p[kb + i];
                    if (dual) p2[i] = B2[(long)bn * ldb + kb + i];
                }
            }
        }
        __syncthreads();   // previous iter's compute done reading LDS
        {
            const float* pa  = (const float*)&av;
            const float* pb1 = (const float*)&bv1;
            const float* pb2 = (const float*)&bv2;
            for (int i = 0; i < 4; i++) {
                As[lk + i][lr]  = pa[i];
                Bs1[lk + i][lr] = pb1[i];
                if (dual) Bs2[lk + i][lr] = pb2[i];
            }
        }
        __syncthreads();
        if (dual) {
            #pragma unroll
            for (int kk = 0; kk < 16; kk++) {
                float4 a  = *(const float4*)&As[kk][ty << 2];
                float4 b1 = *(const float4*)&Bs1[kk][tx << 2];
                float4 b2 = *(const float4*)&Bs2[kk][tx << 2];
                const float aa[4]  = {a.x, a.y, a.z, a.w};
                const float bb1[4] = {b1.x, b1.y, b1.z, b1.w};
                const float bb2[4] = {b2.x, b2.y, b2.z, b2.w};
                for (int i = 0; i < 4; i++)
                    for (int j = 0; j < 4; j++) {
                        acc1[i][j] += aa[i] * bb1[j];
                        acc2[i][j] += aa[i] * bb2[j];
                    }
            }
        } else {
            #pragma unroll
            for (int kk = 0; kk < 16; kk++) {
                float4 a  = *(const float4*)&As[kk][ty << 2];
                float4 b1 = *(const float4*)&Bs1[kk][tx << 2];
                const float aa[4]  = {a.x, a.y, a.z, a.w};
                const float bb1[4] = {b1.x, b1.y, b1.z, b1.w};
                for (int i = 0; i < 4; i++)
                    for (int j = 0; j < 4; j++)
                        acc1[i][j] += aa[i] * bb1[j];
            }
        }
    }

    for (int i = 0; i < 4; i++) {
        int m = m0 + (ty << 2) + i;
        if (m >= M) continue;
        for (int j = 0; j < 4; j++) {
            int n = n0 + (tx << 2) + j;
            if (n >= N) continue;
            float v1 = acc1[i][j] + (bias1 ? bias1[n] : 0.f);
            long  ci = (long)m * N + n;
            if (C1f) C1f[ci] = v1; else C1h[ci] = __float2bfloat16(v1);
            if (dual) {
                float v2 = acc2[i][j] + (bias2 ? bias2[n] : 0.f);
                if (C2f) C2f[ci] = v2; else C2h[ci] = __float2bfloat16(v2);
            }
        }
    }
}

// ---------------- per-sample attention ----------------
// layer1: winner==nullptr, q = HQ[b]+TQ[b], base rows NodeK/V.
// layer2: winner!=nullptr, q = HQ[winner[nodes[b]]]+TQ[b],
//         base rows H1K/H1V[winner[nb]] if winner[nb]>=0 else NodeK/V[nb].
__global__ __launch_bounds__(256) void attn_kernel(
    const int* __restrict__ neighbors,
    const float* __restrict__ TQ, const float* __restrict__ TK, const float* __restrict__ TV,
    const float* __restrict__ HQ,
    const int* __restrict__ nodes, const int* __restrict__ winner,
    const __hip_bfloat16* __restrict__ NodeK, const __hip_bfloat16* __restrict__ NodeV,
    const float* __restrict__ H1K, const float* __restrict__ H1V,
    const __hip_bfloat16* __restrict__ EfK, const __hip_bfloat16* __restrict__ EfV,
    float* __restrict__ attn_out)
{
    const int b = blockIdx.x;
    const int t = threadIdx.x;
    __shared__ float sq[EDIM];
    __shared__ float sk[KNB][EDIM];
    __shared__ float sv[KNB][EDIM];
    __shared__ float sw[2][KNB];
    __shared__ int   snb[KNB];
    __shared__ int   spad[KNB];

    if (t < KNB) {
        int nb = neighbors[b * KNB + t];
        snb[t]  = nb;
        spad[t] = (nb == 0) ? 1 : 0;
    }
    __syncthreads();
    if (t == 0) {   // all-padded row: unmask neighbor 0
        int c = 0;
        for (int k = 0; k < KNB; k++) c += spad[k];
        if (c == KNB) spad[0] = 0;
    }
    if (t < EDIM) {
        float q;
        if (winner) {
            int j = winner[nodes[b]];
            q = HQ[(long)j * EDIM + t] + TQ[(long)b * EDIM + t];
        } else {
            q = HQ[(long)b * EDIM + t] + TQ[(long)b * EDIM + t];
        }
        sq[t] = q;
    }
    for (int li = t; li < KNB * EDIM; li += 256) {
        int kk = li / EDIM, e = li - kk * EDIM;
        int nb = snb[kk];
        float kbv, vbv;
        if (winner) {
            int w = winner[nb];
            if (w >= 0) { kbv = H1K[(long)w * EDIM + e]; vbv = H1V[(long)w * EDIM + e]; }
            else        { kbv = bf2f(NodeK[(long)nb * EDIM + e]); vbv = bf2f(NodeV[(long)nb * EDIM + e]); }
        } else {
            kbv = bf2f(NodeK[(long)nb * EDIM + e]);
            vbv = bf2f(NodeV[(long)nb * EDIM + e]);
        }
        long eoff = ((long)b * KNB + kk) * EDIM + e;
        sk[kk][e] = kbv + TK[(long)b * EDIM + e] + bf2f(EfK[eoff]);
        sv[kk][e] = vbv + TV[(long)b * EDIM + e] + bf2f(EfV[eoff]);
    }
    __syncthreads();

    if (t < 2 * KNB) {                  // 40 dot products of length 86
        int h = t & 1, kk = t >> 1;
        float s = 0.f;
        const float* qp = &sq[h * HDIM];
        const float* kp = &sk[kk][h * HDIM];
        for (int d = 0; d < HDIM; d++) s += qp[d] * kp[d];
        sw[h][kk] = spad[kk] ? -1e9f : (s * 0.10783277320343841f);  // 1/sqrt(86)
    }
    __syncthreads();
    if (t < 2) {                        // softmax per head
        float mx = -1e30f;
        for (int kk = 0; kk < KNB; kk++) mx = fmaxf(mx, sw[t][kk]);
        float sum = 0.f, ex[KNB];
        for (int kk = 0; kk < KNB; kk++) { ex[kk] = expf(sw[t][kk] - mx); sum += ex[kk]; }
        float inv = 1.f / sum;
        for (int kk = 0; kk < KNB; kk++) sw[t][kk] = ex[kk] * inv;
    }
    __syncthreads();
    if (t < EDIM) {
        int h = t / HDIM;
        float acc = 0.f;
        for (int kk = 0; kk < KNB; kk++) acc += sw[h][kk] * sv[kk][t];
        attn_out[(long)b * EDIM + t] = acc;
    }
}

extern "C" void kernel_launch(void* const* d_in, const int* in_sizes, int n_in,
                              void* d_out, int out_size, void* d_ws, size_t ws_size,
                              hipStream_t stream)
{
    const int*   nodes   = (const int*)d_in[0];
    const float* ts      = (const float*)d_in[1];
    const int*   neigh   = (const int*)d_in[2];
    const int*   edgeidx = (const int*)d_in[3];
    const float* nodef   = (const float*)d_in[4];
    const float* edgef   = (const float*)d_in[5];
    const float* time_w  = (const float*)d_in[6];
    const float* time_b  = (const float*)d_in[7];
    const float* q_w     = (const float*)d_in[8];
    const float* k_w     = (const float*)d_in[9];
    const float* v_w     = (const float*)d_in[10];
    const float* bq      = (const float*)d_in[11];
    const float* bk      = (const float*)d_in[12];
    const float* bv      = (const float*)d_in[13];
    const float* out_w   = (const float*)d_in[14];
    const float* out_b   = (const float*)d_in[15];
    float* out = (float*)d_out;

    char* wsp = (char*)d_ws;
    size_t off = 0;
    auto alloc = [&](size_t bytes) -> void* {
        void* p = wsp + off;
        off += (bytes + 255) & ~(size_t)255;
        return p;
    };
    const size_t SE = (size_t)NSMP * EDIM;
    float* t_enc = (float*)alloc(SE * 4);
    float* TQ    = (float*)alloc(SE * 4);
    float* TK    = (float*)alloc(SE * 4);
    float* TV    = (float*)alloc(SE * 4);
    float* HQ    = (float*)alloc(SE * 4);
    float* AO    = (float*)alloc(SE * 4);
    float* H1    = (float*)alloc(SE * 4);
    float* H1Q   = (float*)alloc(SE * 4);
    float* H1K   = (float*)alloc(SE * 4);
    float* H1V   = (float*)alloc(SE * 4);
    int*   winner = (int*)alloc((size_t)NNODES * 4);
    __hip_bfloat16* NodeK = (__hip_bfloat16*)alloc((size_t)NNODES * EDIM * 2);
    __hip_bfloat16* NodeV = (__hip_bfloat16*)alloc((size_t)NNODES * EDIM * 2);
    __hip_bfloat16* EfK   = (__hip_bfloat16*)alloc((size_t)NSMP * KNB * EDIM * 2);
    __hip_bfloat16* EfV   = (__hip_bfloat16*)alloc((size_t)NSMP * KNB * EDIM * 2);
    if (off > ws_size) return;  // workspace too small: fail visibly (poisoned d_out)

    const int ldkw = EDIM + EDIM;  // 344
    dim3 blk(256);
    dim3 gB((EDIM + 63) / 64, (NSMP + 63) / 64);            // 3 x 188
    dim3 gN((EDIM + 63) / 64, (NNODES + 63) / 64);          // 3 x 1563
    dim3 gE((EDIM + 63) / 64, (NSMP * KNB + 63) / 64);      // 3 x 3750

    time_enc_kernel<<<(NSMP * EDIM + 255) / 256, blk, 0, stream>>>(ts, time_w, time_b, t_enc);

    // TQ = t@q_w.T + bq
    gemm_nt_kernel<<<gB, blk, 0, stream>>>(t_enc, nullptr, EDIM, NSMP,
        q_w, nullptr, EDIM, bq, nullptr,
        TQ, nullptr, nullptr, nullptr, EDIM, EDIM);
    // TK/TV = t@{k,v}_wE.T + bk/bv
    gemm_nt_kernel<<<gB, blk, 0, stream>>>(t_enc, nullptr, EDIM, NSMP,
        k_w, v_w, ldkw, bk, bv,
        TK, nullptr, TV, nullptr, EDIM, EDIM);
    // NodeK/V = node_features@{k,v}_wE.T  (bf16)
    gemm_nt_kernel<<<gN, blk, 0, stream>>>(nodef, nullptr, EDIM, NNODES,
        k_w, v_w, ldkw, nullptr, nullptr,
        nullptr, NodeK, nullptr, NodeV, EDIM, EDIM);
    // EfK/V = edge_features[edgeidx]@{k,v}_wDE.T  (bf16)
    gemm_nt_kernel<<<gE, blk, 0, stream>>>(edgef, edgeidx, EDIM, NSMP * KNB,
        k_w + EDIM, v_w + EDIM, ldkw, nullptr, nullptr,
        nullptr, EfK, nullptr, EfV, EDIM, EDIM);
    // HQ = node_features[nodes]@q_w.T
    gemm_nt_kernel<<<gB, blk, 0, stream>>>(nodef, nodes, EDIM, NSMP,
        q_w, nullptr, EDIM, nullptr, nullptr,
        HQ, nullptr, nullptr, nullptr, EDIM, EDIM);

    // layer 1 attention
    attn_kernel<<<NSMP, blk, 0, stream>>>(neigh, TQ, TK, TV, HQ,
        nullptr, nullptr, NodeK, NodeV, nullptr, nullptr, EfK, EfV, AO);
    // h1 = AO@out_w.T + out_b
    gemm_nt_kernel<<<gB, blk, 0, stream>>>(AO, nullptr, EDIM, NSMP,
        out_w, nullptr, EDIM, out_b, nullptr,
        H1, nullptr, nullptr, nullptr, EDIM, EDIM);

    // scatter winners (numpy last-write-wins)
    winner_init_kernel<<<(NNODES + 255) / 256, blk, 0, stream>>>(winner);
    winner_scatter_kernel<<<(NSMP + 255) / 256, blk, 0, stream>>>(nodes, winner);

    // layer-2 projections of h1
    gemm_nt_kernel<<<gB, blk, 0, stream>>>(H1, nullptr, EDIM, NSMP,
        q_w, nullptr, EDIM, nullptr, nullptr,
        H1Q, nullptr, nullptr, nullptr, EDIM, EDIM);
    gemm_nt_kernel<<<gB, blk, 0, stream>>>(H1, nullptr, EDIM, NSMP,
        k_w, v_w, ldkw, nullptr, nullptr,
        H1K, nullptr, H1V, nullptr, EDIM, EDIM);

    // layer 2 attention
    attn_kernel<<<NSMP, blk, 0, stream>>>(neigh, TQ, TK, TV, H1Q,
        nodes, winner, NodeK, NodeV, H1K, H1V, EfK, EfV, AO);
    // final = AO@out_w.T + out_b -> d_out (f32, 12000x172 flat == concat of 3 outputs)
    gemm_nt_kernel<<<gB, blk, 0, stream>>>(AO, nullptr, EDIM, NSMP,
        out_w, nullptr, EDIM, out_b, nullptr,
        out, nullptr, nullptr, nullptr, EDIM, EDIM);
}